// Round 13
// baseline (36.182 us; speedup 1.0000x reference)
//
#include <hip/hip_runtime.h>

#define NPTS   384
#define DIM    256
#define GA     6              // anchors per block
#define NBLK   64             // blocks (64 atomics total -> ~2us ticket tail)
#define NTHR   512            // 8 waves
#define MAXK   64             // cap on same-class count (expected ~12)
#define MARGIN 1.0f

__device__ __forceinline__ float wave_red_sum(float p) {
    #pragma unroll
    for (int m = 1; m < 64; m <<= 1) p += __shfl_xor(p, m, 64);
    return p;
}

// Single work kernel (R10 structure, grid.sync -> R5-proven ticket).
// Block b owns anchors [6b, 6b+6):
//  - 6 anchor fragments in registers; each of 384 rows loaded once per block,
//    dotted vs all 6 anchors (quarter-wave 16-lane dots)
//  - dj[a][*] holds the FULL d-row -> positives are dj[a][kidx[a][t]], free
//  - waves 0..5 ballot-compact positives of anchor a0+w
//  - hinge per thread-j, block reduce, partial[b] store, 64-atomic ticket,
//    last block reduces 64 partials -> out. Ticket zeroed by memset node.
__global__ __launch_bounds__(NTHR) void triplet_one(const float* __restrict__ x,
                                                    const int* __restrict__ labels,
                                                    float2* __restrict__ partial,
                                                    unsigned int* __restrict__ ticket,
                                                    float* __restrict__ out) {
    const int b    = blockIdx.x;
    const int tid  = threadIdx.x;
    const int lane = tid & 63;
    const int wid  = tid >> 6;    // 0..7
    const int sub  = lane >> 4;   // row within 4-row group
    const int l16  = lane & 15;   // element-slice lane
    const int a0   = b * GA;

    __shared__ int   lab[NPTS];
    __shared__ float dj[GA][NPTS];
    __shared__ int   kidx[GA][MAXK];
    __shared__ int   nk_sh[GA];
    __shared__ float wnum[8], wcnt[8];
    __shared__ int   last_sh;

    for (int j = tid; j < NPTS; j += NTHR) lab[j] = labels[j];

    // anchor fragments: fa[t][q] = x[a0+t][l16*4 + q*64 .. +4)
    float4 fa[GA][4];
    #pragma unroll
    for (int t = 0; t < GA; ++t)
        #pragma unroll
        for (int q = 0; q < 4; ++q)
            fa[t][q] = *(const float4*)(x + (size_t)(a0 + t) * DIM + l16 * 4 + q * 64);

    // waves 0..5: ballot-compact positives of anchor a0+wid (global reads)
    if (wid < GA) {
        const int li = labels[a0 + wid];
        int base = 0;
        #pragma unroll
        for (int c = 0; c < 6; ++c) {
            const bool m = (labels[c * 64 + lane] == li);
            const unsigned long long mk = __ballot(m);
            const int pre = __popcll(mk & ((1ull << lane) - 1ull));
            const int p = base + pre;
            if (m && p < MAXK) kidx[wid][p] = c * 64 + lane;
            base += __popcll(mk);          // wave-uniform
        }
        if (lane == 0) nk_sh[wid] = (base > MAXK) ? MAXK : base;
    }

    // dots: 8 waves x 4 rows = 32 rows/iter, 12 iters; one load -> 6 dots
    #pragma unroll 2
    for (int u = 0; u < NPTS / 32; ++u) {
        const int r = u * 32 + wid * 4 + sub;
        const float* xr = x + (size_t)r * DIM + l16 * 4;
        float4 rx[4];
        #pragma unroll
        for (int q = 0; q < 4; ++q) rx[q] = *(const float4*)(xr + q * 64);
        #pragma unroll
        for (int t = 0; t < GA; ++t) {
            float acc = 0.f;
            #pragma unroll
            for (int q = 0; q < 4; ++q) {
                const float d0 = rx[q].x - fa[t][q].x, d1 = rx[q].y - fa[t][q].y,
                            d2 = rx[q].z - fa[t][q].z, d3 = rx[q].w - fa[t][q].w;
                acc += d0*d0 + d1*d1 + d2*d2 + d3*d3;
            }
            #pragma unroll
            for (int m = 1; m < 16; m <<= 1) acc += __shfl_xor(acc, m, 64);
            if (l16 == 0) dj[t][r] = acc;
        }
    }
    __syncthreads();

    // hinge: thread j = tid (tid<384); positives read from dj via kidx
    float num = 0.f, cnt = 0.f;
    if (tid < NPTS) {
        #pragma unroll
        for (int a = 0; a < GA; ++a) {
            const int li = lab[a0 + a];
            if (lab[tid] != li) {
                const float bb = dj[a][tid] - MARGIN;
                const int nk = nk_sh[a];
                for (int t = 0; t < nk; ++t) {
                    const float h = bb + dj[a][kidx[a][t]];  // uniform broadcasts
                    num += (h > 0.f) ? h : 0.f;
                }
                cnt += (float)nk;
            }
        }
    }
    num = wave_red_sum(num);
    cnt = wave_red_sum(cnt);
    if (lane == 0) { wnum[wid] = num; wcnt[wid] = cnt; }
    __syncthreads();
    if (tid == 0) {
        float n = 0.f, c = 0.f;
        #pragma unroll
        for (int w = 0; w < 8; ++w) { n += wnum[w]; c += wcnt[w]; }
        partial[b] = make_float2(n, c);
        __threadfence();                                 // release partial
        const unsigned int old = atomicAdd(ticket, 1u);  // 64 RMWs total
        last_sh = (old == NBLK - 1) ? 1 : 0;
    }
    __syncthreads();

    if (last_sh && tid < 64) {
        __threadfence();                                 // acquire partials
        const float2 v = partial[tid];                   // NBLK == 64 == one wave
        float n = v.x, c = v.y;
        #pragma unroll
        for (int m = 1; m < 64; m <<= 1) {
            n += __shfl_xor(n, m, 64);
            c += __shfl_xor(c, m, 64);
        }
        if (tid == 0) out[0] = n / c;
    }
}

extern "C" void kernel_launch(void* const* d_in, const int* in_sizes, int n_in,
                              void* d_out, int out_size, void* d_ws, size_t ws_size,
                              hipStream_t stream) {
    const float* x      = (const float*)d_in[0];
    const int*   labels = (const int*)d_in[1];
    float*       out    = (float*)d_out;

    float2*       partial = (float2*)d_ws;
    unsigned int* ticket  = (unsigned int*)(partial + NBLK);

    hipMemsetAsync(ticket, 0, sizeof(unsigned int), stream);
    triplet_one<<<NBLK, NTHR, 0, stream>>>(x, labels, partial, ticket, out);
}

// Round 14
// 32.907 us; speedup vs baseline: 1.0995x; 1.0995x over previous
//
#include <hip/hip_runtime.h>

#define NPTS    384
#define DIM     256
#define GA      4              // anchors per block (register-resident fragments)
#define NGRP    (NPTS/GA)      // 96 anchor groups
#define SPLIT   8              // j-slices
#define JS      (NPTS/SPLIT)   // 48 j's per block
#define NBLK    (NGRP*SPLIT)   // 768 blocks = 3/CU
#define MAXK    64             // cap on same-class count (expected ~12)
#define NSHARD  8              // ticket shards (one cacheline each)
#define PERSH   (NBLK/NSHARD)  // 96 RMWs per shard line
#define MARGIN  1.0f

__device__ __forceinline__ float wave_red_sum(float p) {
    #pragma unroll
    for (int m = 1; m < 64; m <<= 1) p += __shfl_xor(p, m, 64);
    return p;
}

// R9's proven main (best: 17.34 us total) with the finalize NODE replaced by a
// sharded-ticket self-finalize: 96 atomics per cacheline x 8 lines (parallel
// across TCC channels) + 8 master RMWs; last block reduces 768 partials -> out.
__global__ __launch_bounds__(256) void triplet_main(const float* __restrict__ x,
                                                    const int* __restrict__ labels,
                                                    float2* __restrict__ partial,
                                                    unsigned int* __restrict__ ticket,
                                                    float* __restrict__ out) {
    const int g    = blockIdx.x;
    const int s    = blockIdx.y;
    const int tid  = threadIdx.x;
    const int lane = tid & 63;
    const int wid  = tid >> 6;
    const int sub  = lane >> 4;   // row within 4-row group
    const int l16  = lane & 15;   // element-slice lane
    const int a0   = g * GA;

    __shared__ int   lab[NPTS];
    __shared__ int   kidx[GA][MAXK];
    __shared__ float dk[GA][MAXK];
    __shared__ float dj[GA][JS];
    __shared__ int   nk_sh[GA];
    __shared__ float wnum[4], wcnt[4];
    __shared__ int   last_sh;

    for (int j = tid; j < NPTS; j += 256) lab[j] = labels[j];

    // anchor fragments: fa[t][q] = x[a0+t][l16*4 + q*64 .. +4)
    float4 fa[GA][4];
    #pragma unroll
    for (int t = 0; t < GA; ++t)
        #pragma unroll
        for (int q = 0; q < 4; ++q)
            fa[t][q] = *(const float4*)(x + (size_t)(a0 + t) * DIM + l16 * 4 + q * 64);

    // wave w: ballot-compact positives of anchor a0+w (global label reads)
    {
        const int li = labels[a0 + wid];
        int base = 0;
        #pragma unroll
        for (int c = 0; c < 6; ++c) {
            const bool m = (labels[c * 64 + lane] == li);
            const unsigned long long mk = __ballot(m);
            const int pre = __popcll(mk & ((1ull << lane) - 1ull));
            const int p = base + pre;
            if (m && p < MAXK) kidx[wid][p] = c * 64 + lane;
            base += __popcll(mk);          // wave-uniform
        }
        if (lane == 0) nk_sh[wid] = (base > MAXK) ? MAXK : base;
    }
    __syncthreads();

    // slice dots: 16 rows/block-iter, 3 iters; one row load -> 4 anchor dots
    #pragma unroll
    for (int u = 0; u < JS / 16; ++u) {
        const int rl = u * 16 + wid * 4 + sub;           // 0..47
        const float* xr = x + (size_t)(s * JS + rl) * DIM + l16 * 4;
        float4 rx[4];
        #pragma unroll
        for (int q = 0; q < 4; ++q) rx[q] = *(const float4*)(xr + q * 64);
        #pragma unroll
        for (int t = 0; t < GA; ++t) {
            float acc = 0.f;
            #pragma unroll
            for (int q = 0; q < 4; ++q) {
                const float d0 = rx[q].x - fa[t][q].x, d1 = rx[q].y - fa[t][q].y,
                            d2 = rx[q].z - fa[t][q].z, d3 = rx[q].w - fa[t][q].w;
                acc += d0*d0 + d1*d1 + d2*d2 + d3*d3;
            }
            #pragma unroll
            for (int m = 1; m < 16; m <<= 1) acc += __shfl_xor(acc, m, 64);
            if (l16 == 0) dj[t][rl] = acc;
        }
    }

    // positive dots: 16 groups (wid,sub) cover each anchor's list (1 iter typ.)
    #pragma unroll
    for (int a = 0; a < GA; ++a) {
        const int nk = nk_sh[a];
        for (int t0 = 0; t0 < nk; t0 += 16) {
            const int t = t0 + wid * 4 + sub;
            if (t < nk) {                    // whole 16-lane group together
                const float* xr = x + (size_t)kidx[a][t] * DIM + l16 * 4;
                float acc = 0.f;
                #pragma unroll
                for (int q = 0; q < 4; ++q) {
                    const float4 rv = *(const float4*)(xr + q * 64);
                    const float d0 = rv.x - fa[a][q].x, d1 = rv.y - fa[a][q].y,
                                d2 = rv.z - fa[a][q].z, d3 = rv.w - fa[a][q].w;
                    acc += d0*d0 + d1*d1 + d2*d2 + d3*d3;
                }
                #pragma unroll
                for (int m = 1; m < 16; m <<= 1) acc += __shfl_xor(acc, m, 64);
                if (l16 == 0) dk[a][t] = acc;
            }
        }
    }
    __syncthreads();

    // hinge: 192 (a, jl) pairs, threads 0..191
    float num = 0.f, cnt = 0.f;
    if (tid < GA * JS) {
        const int a  = tid / JS;
        const int jl = tid % JS;
        const int li = lab[a0 + a];
        if (lab[s * JS + jl] != li) {
            const int nk = nk_sh[a];
            const float b = dj[a][jl] - MARGIN;
            for (int t = 0; t < nk; ++t) {
                const float h = b + dk[a][t];
                num += (h > 0.f) ? h : 0.f;
            }
            cnt = (float)nk;
        }
    }
    num = wave_red_sum(num);
    cnt = wave_red_sum(cnt);
    if (lane == 0) { wnum[wid] = num; wcnt[wid] = cnt; }
    __syncthreads();

    const int lid = blockIdx.y * gridDim.x + blockIdx.x;   // 0..767
    if (tid == 0) {
        partial[lid] = make_float2(wnum[0] + wnum[1] + wnum[2] + wnum[3],
                                   wcnt[0] + wcnt[1] + wcnt[2] + wcnt[3]);
        __threadfence();                                    // release partial
        int last = 0;
        const unsigned int o1 = atomicAdd(&ticket[(lid & (NSHARD - 1)) * 16], 1u);
        if (o1 == PERSH - 1) {                              // shard complete
            const unsigned int o2 = atomicAdd(&ticket[NSHARD * 16], 1u);
            last = (o2 == NSHARD - 1);
        }
        last_sh = last;
    }
    __syncthreads();

    if (last_sh) {                      // final block: deterministic reduce
        __threadfence();                // acquire all partials
        float n = 0.f, c = 0.f;
        for (int p = tid; p < NBLK; p += 256) {
            const float2 v = partial[p];
            n += v.x; c += v.y;
        }
        n = wave_red_sum(n);
        c = wave_red_sum(c);
        if (lane == 0) { wnum[wid] = n; wcnt[wid] = c; }
        __syncthreads();
        if (tid == 0)
            out[0] = (wnum[0] + wnum[1] + wnum[2] + wnum[3]) /
                     (wcnt[0] + wcnt[1] + wcnt[2] + wcnt[3]);
    }
}

extern "C" void kernel_launch(void* const* d_in, const int* in_sizes, int n_in,
                              void* d_out, int out_size, void* d_ws, size_t ws_size,
                              hipStream_t stream) {
    const float* x      = (const float*)d_in[0];
    const int*   labels = (const int*)d_in[1];
    float*       out    = (float*)d_out;

    float2*       partial = (float2*)d_ws;                       // 6 KB
    unsigned int* ticket  = (unsigned int*)(partial + NBLK);     // 9 x 64B lines

    hipMemsetAsync(ticket, 0, (NSHARD + 1) * 16 * sizeof(unsigned int), stream);
    dim3 grid(NGRP, SPLIT);
    triplet_main<<<grid, 256, 0, stream>>>(x, labels, partial, ticket, out);
}

// Round 15
// 21.297 us; speedup vs baseline: 1.6989x; 1.5451x over previous
//
#include <hip/hip_runtime.h>

#define NPTS   384
#define DIM    256
#define GA     4              // anchors per block (register-resident fragments)
#define NGRP   (NPTS/GA)      // 96 anchor groups
#define SPLIT  8              // j-slices
#define JS     (NPTS/SPLIT)   // 48 j's per block
#define NBLK   (NGRP*SPLIT)   // 768 blocks
#define NTHR   512            // 8 waves -> 24 waves/CU (vs R9's 12)
#define MAXK   64             // cap on same-class count (expected ~12)
#define MARGIN 1.0f

__device__ __forceinline__ float wave_red_sum(float p) {
    #pragma unroll
    for (int m = 1; m < 64; m <<= 1) p += __shfl_xor(p, m, 64);
    return p;
}

// R9's proven structure widened to 8 waves/block: same blocks, same traffic,
// halved per-block serial phases, doubled per-CU wave count.
//   waves 0-3: ballot-compact anchor a0+wid -> dot iter0 rows 0-15 -> pos dots
//   waves 4-7: dot iter0 rows 16-31 -> dot iter1 rows 32-47
__global__ __launch_bounds__(NTHR) void triplet_main(const float* __restrict__ x,
                                                     const int* __restrict__ labels,
                                                     float2* __restrict__ partial) {
    const int g    = blockIdx.x;
    const int s    = blockIdx.y;
    const int tid  = threadIdx.x;
    const int lane = tid & 63;
    const int wid  = tid >> 6;    // 0..7
    const int sub  = lane >> 4;   // row within 4-row group
    const int l16  = lane & 15;   // element-slice lane
    const int a0   = g * GA;

    __shared__ int   lab[NPTS];
    __shared__ int   kidx[GA][MAXK];
    __shared__ float dk[GA][MAXK];
    __shared__ float dj[GA][JS];
    __shared__ int   nk_sh[GA];
    __shared__ float wnum[8], wcnt[8];

    for (int j = tid; j < NPTS; j += NTHR) lab[j] = labels[j];

    // anchor fragments: fa[t][q] = x[a0+t][l16*4 + q*64 .. +4)
    float4 fa[GA][4];
    #pragma unroll
    for (int t = 0; t < GA; ++t)
        #pragma unroll
        for (int q = 0; q < 4; ++q)
            fa[t][q] = *(const float4*)(x + (size_t)(a0 + t) * DIM + l16 * 4 + q * 64);

    if (wid < GA) {
        // waves 0-3: ballot-compact positives of anchor a0+wid
        const int li = labels[a0 + wid];
        int base = 0;
        #pragma unroll
        for (int c = 0; c < 6; ++c) {
            const bool m = (labels[c * 64 + lane] == li);
            const unsigned long long mk = __ballot(m);
            const int pre = __popcll(mk & ((1ull << lane) - 1ull));
            const int p = base + pre;
            if (m && p < MAXK) kidx[wid][p] = c * 64 + lane;
            base += __popcll(mk);          // wave-uniform
        }
        if (lane == 0) nk_sh[wid] = (base > MAXK) ? MAXK : base;

        // dot iter0 (their share): rows 0..15
        const int rl = wid * 4 + sub;
        const float* xr = x + (size_t)(s * JS + rl) * DIM + l16 * 4;
        float4 rx[4];
        #pragma unroll
        for (int q = 0; q < 4; ++q) rx[q] = *(const float4*)(xr + q * 64);
        #pragma unroll
        for (int t = 0; t < GA; ++t) {
            float acc = 0.f;
            #pragma unroll
            for (int q = 0; q < 4; ++q) {
                const float d0 = rx[q].x - fa[t][q].x, d1 = rx[q].y - fa[t][q].y,
                            d2 = rx[q].z - fa[t][q].z, d3 = rx[q].w - fa[t][q].w;
                acc += d0*d0 + d1*d1 + d2*d2 + d3*d3;
            }
            #pragma unroll
            for (int m = 1; m < 16; m <<= 1) acc += __shfl_xor(acc, m, 64);
            if (l16 == 0) dj[t][rl] = acc;
        }

        // positive dots: 16 groups across waves 0-3 (1 iter typical)
        #pragma unroll
        for (int a = 0; a < GA; ++a) {
            const int nk = nk_sh[a];
            for (int t0 = 0; t0 < nk; t0 += 16) {
                const int t = t0 + wid * 4 + sub;
                if (t < nk) {                // whole 16-lane group together
                    const float* xp = x + (size_t)kidx[a][t] * DIM + l16 * 4;
                    float acc = 0.f;
                    #pragma unroll
                    for (int q = 0; q < 4; ++q) {
                        const float4 rv = *(const float4*)(xp + q * 64);
                        const float d0 = rv.x - fa[a][q].x, d1 = rv.y - fa[a][q].y,
                                    d2 = rv.z - fa[a][q].z, d3 = rv.w - fa[a][q].w;
                        acc += d0*d0 + d1*d1 + d2*d2 + d3*d3;
                    }
                    #pragma unroll
                    for (int m = 1; m < 16; m <<= 1) acc += __shfl_xor(acc, m, 64);
                    if (l16 == 0) dk[a][t] = acc;
                }
            }
        }
    } else {
        // waves 4-7: dot iters for rows 16..31 and 32..47
        #pragma unroll
        for (int u = 0; u < 2; ++u) {
            const int rl = 16 * u + (wid - 4) * 4 + sub + 16;   // 16..31, 32..47
            const float* xr = x + (size_t)(s * JS + rl) * DIM + l16 * 4;
            float4 rx[4];
            #pragma unroll
            for (int q = 0; q < 4; ++q) rx[q] = *(const float4*)(xr + q * 64);
            #pragma unroll
            for (int t = 0; t < GA; ++t) {
                float acc = 0.f;
                #pragma unroll
                for (int q = 0; q < 4; ++q) {
                    const float d0 = rx[q].x - fa[t][q].x, d1 = rx[q].y - fa[t][q].y,
                                d2 = rx[q].z - fa[t][q].z, d3 = rx[q].w - fa[t][q].w;
                    acc += d0*d0 + d1*d1 + d2*d2 + d3*d3;
                }
                #pragma unroll
                for (int m = 1; m < 16; m <<= 1) acc += __shfl_xor(acc, m, 64);
                if (l16 == 0) dj[t][rl] = acc;
            }
        }
    }
    __syncthreads();

    // hinge: 192 (a, jl) pairs on threads 0..191 (waves 0-2)
    float num = 0.f, cnt = 0.f;
    if (tid < GA * JS) {
        const int a  = tid / JS;
        const int jl = tid % JS;
        const int li = lab[a0 + a];
        if (lab[s * JS + jl] != li) {
            const int nk = nk_sh[a];
            const float b = dj[a][jl] - MARGIN;
            for (int t = 0; t < nk; ++t) {
                const float h = b + dk[a][t];
                num += (h > 0.f) ? h : 0.f;
            }
            cnt = (float)nk;
        }
    }
    if (wid < 3) {
        num = wave_red_sum(num);
        cnt = wave_red_sum(cnt);
        if (lane == 0) { wnum[wid] = num; wcnt[wid] = cnt; }
    }
    __syncthreads();
    if (tid == 0)
        partial[blockIdx.y * gridDim.x + blockIdx.x] =
            make_float2(wnum[0] + wnum[1] + wnum[2],
                        wcnt[0] + wcnt[1] + wcnt[2]);
}

__global__ __launch_bounds__(256) void triplet_finalize(const float2* __restrict__ partial,
                                                        float* __restrict__ out) {
    const int tid = threadIdx.x, lane = tid & 63, wid = tid >> 6;
    __shared__ float wnum[4], wcnt[4];
    float n = 0.f, c = 0.f;
    for (int p = tid; p < NBLK; p += 256) {
        const float2 v = partial[p];
        n += v.x; c += v.y;
    }
    n = wave_red_sum(n);
    c = wave_red_sum(c);
    if (lane == 0) { wnum[wid] = n; wcnt[wid] = c; }
    __syncthreads();
    if (tid == 0)
        out[0] = (wnum[0] + wnum[1] + wnum[2] + wnum[3]) /
                 (wcnt[0] + wcnt[1] + wcnt[2] + wcnt[3]);
}

extern "C" void kernel_launch(void* const* d_in, const int* in_sizes, int n_in,
                              void* d_out, int out_size, void* d_ws, size_t ws_size,
                              hipStream_t stream) {
    const float* x      = (const float*)d_in[0];
    const int*   labels = (const int*)d_in[1];
    float*       out    = (float*)d_out;

    float2* partial = (float2*)d_ws;

    dim3 grid(NGRP, SPLIT);
    triplet_main<<<grid, NTHR, 0, stream>>>(x, labels, partial);
    triplet_finalize<<<1, 256, 0, stream>>>(partial, out);
}

// Round 16
// 16.641 us; speedup vs baseline: 2.1743x; 1.2798x over previous
//
#include <hip/hip_runtime.h>

#define NPTS   384
#define DIM    256
#define GA     4              // anchors per block (register-resident fragments)
#define NGRP   (NPTS/GA)      // 96 anchor groups
#define SPLIT  8              // j-slices
#define JS     (NPTS/SPLIT)   // 48 j's per block
#define NBLK   (NGRP*SPLIT)   // 768 blocks = 3/CU
#define MAXK   64             // cap on same-class count (expected ~12)
#define MARGIN 1.0f

__device__ __forceinline__ float wave_red_sum(float p) {
    #pragma unroll
    for (int m = 1; m < 64; m <<= 1) p += __shfl_xor(p, m, 64);
    return p;
}

// R9 verbatim (best measured: 17.34 us total). Block (g, s): anchors
// a0..a0+3, j-slice s (48 rows). 4 register-resident anchor fragments;
// each slice row loaded once, dotted vs all 4 anchors (quarter-wave dots);
// per-wave ballot compaction; 16-lane-group positive dots; fused hinge.
__global__ __launch_bounds__(256) void triplet_main(const float* __restrict__ x,
                                                    const int* __restrict__ labels,
                                                    float2* __restrict__ partial) {
    const int g    = blockIdx.x;
    const int s    = blockIdx.y;
    const int tid  = threadIdx.x;
    const int lane = tid & 63;
    const int wid  = tid >> 6;
    const int sub  = lane >> 4;   // row within 4-row group
    const int l16  = lane & 15;   // element-slice lane
    const int a0   = g * GA;

    __shared__ int   lab[NPTS];
    __shared__ int   kidx[GA][MAXK];
    __shared__ float dk[GA][MAXK];
    __shared__ float dj[GA][JS];
    __shared__ int   nk_sh[GA];
    __shared__ float wnum[4], wcnt[4];

    for (int j = tid; j < NPTS; j += 256) lab[j] = labels[j];

    // anchor fragments: fa[t][q] = x[a0+t][l16*4 + q*64 .. +4)
    float4 fa[GA][4];
    #pragma unroll
    for (int t = 0; t < GA; ++t)
        #pragma unroll
        for (int q = 0; q < 4; ++q)
            fa[t][q] = *(const float4*)(x + (size_t)(a0 + t) * DIM + l16 * 4 + q * 64);

    // wave w: ballot-compact positives of anchor a0+w (global label reads)
    {
        const int li = labels[a0 + wid];
        int base = 0;
        #pragma unroll
        for (int c = 0; c < 6; ++c) {
            const bool m = (labels[c * 64 + lane] == li);
            const unsigned long long mk = __ballot(m);
            const int pre = __popcll(mk & ((1ull << lane) - 1ull));
            const int p = base + pre;
            if (m && p < MAXK) kidx[wid][p] = c * 64 + lane;
            base += __popcll(mk);          // wave-uniform
        }
        if (lane == 0) nk_sh[wid] = (base > MAXK) ? MAXK : base;
    }
    __syncthreads();

    // slice dots: 16 rows/block-iter, 3 iters; one row load -> 4 anchor dots
    #pragma unroll
    for (int u = 0; u < JS / 16; ++u) {
        const int rl = u * 16 + wid * 4 + sub;           // 0..47
        const float* xr = x + (size_t)(s * JS + rl) * DIM + l16 * 4;
        float4 rx[4];
        #pragma unroll
        for (int q = 0; q < 4; ++q) rx[q] = *(const float4*)(xr + q * 64);
        #pragma unroll
        for (int t = 0; t < GA; ++t) {
            float acc = 0.f;
            #pragma unroll
            for (int q = 0; q < 4; ++q) {
                const float d0 = rx[q].x - fa[t][q].x, d1 = rx[q].y - fa[t][q].y,
                            d2 = rx[q].z - fa[t][q].z, d3 = rx[q].w - fa[t][q].w;
                acc += d0*d0 + d1*d1 + d2*d2 + d3*d3;
            }
            #pragma unroll
            for (int m = 1; m < 16; m <<= 1) acc += __shfl_xor(acc, m, 64);
            if (l16 == 0) dj[t][rl] = acc;
        }
    }

    // positive dots: 16 groups (wid,sub) cover each anchor's list (1 iter typ.)
    #pragma unroll
    for (int a = 0; a < GA; ++a) {
        const int nk = nk_sh[a];
        for (int t0 = 0; t0 < nk; t0 += 16) {
            const int t = t0 + wid * 4 + sub;
            if (t < nk) {                    // whole 16-lane group together
                const float* xr = x + (size_t)kidx[a][t] * DIM + l16 * 4;
                float acc = 0.f;
                #pragma unroll
                for (int q = 0; q < 4; ++q) {
                    const float4 rv = *(const float4*)(xr + q * 64);
                    const float d0 = rv.x - fa[a][q].x, d1 = rv.y - fa[a][q].y,
                                d2 = rv.z - fa[a][q].z, d3 = rv.w - fa[a][q].w;
                    acc += d0*d0 + d1*d1 + d2*d2 + d3*d3;
                }
                #pragma unroll
                for (int m = 1; m < 16; m <<= 1) acc += __shfl_xor(acc, m, 64);
                if (l16 == 0) dk[a][t] = acc;
            }
        }
    }
    __syncthreads();

    // hinge: 192 (a, jl) pairs, threads 0..191
    float num = 0.f, cnt = 0.f;
    if (tid < GA * JS) {
        const int a  = tid / JS;
        const int jl = tid % JS;
        const int li = lab[a0 + a];
        if (lab[s * JS + jl] != li) {
            const int nk = nk_sh[a];
            const float b = dj[a][jl] - MARGIN;
            for (int t = 0; t < nk; ++t) {
                const float h = b + dk[a][t];
                num += (h > 0.f) ? h : 0.f;
            }
            cnt = (float)nk;
        }
    }
    num = wave_red_sum(num);
    cnt = wave_red_sum(cnt);
    if (lane == 0) { wnum[wid] = num; wcnt[wid] = cnt; }
    __syncthreads();
    if (tid == 0)
        partial[blockIdx.y * gridDim.x + blockIdx.x] =
            make_float2(wnum[0] + wnum[1] + wnum[2] + wnum[3],
                        wcnt[0] + wcnt[1] + wcnt[2] + wcnt[3]);
}

// Slim finalize: ONE wave, 12 float2 loads/lane, pure shfl butterfly.
// No LDS, no barriers -> shortest possible tail node.
__global__ __launch_bounds__(64) void triplet_finalize(const float2* __restrict__ partial,
                                                       float* __restrict__ out) {
    const int lane = threadIdx.x;
    float n = 0.f, c = 0.f;
    #pragma unroll
    for (int u = 0; u < NBLK / 64; ++u) {
        const float2 v = partial[u * 64 + lane];
        n += v.x; c += v.y;
    }
    n = wave_red_sum(n);
    c = wave_red_sum(c);
    if (lane == 0) out[0] = n / c;
}

extern "C" void kernel_launch(void* const* d_in, const int* in_sizes, int n_in,
                              void* d_out, int out_size, void* d_ws, size_t ws_size,
                              hipStream_t stream) {
    const float* x      = (const float*)d_in[0];
    const int*   labels = (const int*)d_in[1];
    float*       out    = (float*)d_out;

    float2* partial = (float2*)d_ws;

    dim3 grid(NGRP, SPLIT);
    triplet_main<<<grid, 256, 0, stream>>>(x, labels, partial);
    triplet_finalize<<<1, 64, 0, stream>>>(partial, out);
}